// Round 6
// baseline (245.605 us; speedup 1.0000x reference)
//
#include <hip/hip_runtime.h>

// PointPillarScatter on MI355X — gather formulation, fused prep.
//   out[b, c, g] = pf[b, c, p] where coords maps pillar row i=(b,p) -> spatial g (g>0), else 0.
// Pipeline (3 dispatches):
//   1) memset inv[] (d_ws) to -1                                   (3.4 MB, ~1.5 us)
//   2) prep: blocks [0,188)   -> inv[b*G + s] = pillar row i
//            blocks [188,940) -> feats_t[i][c] = pf[b_i, c, p_i]   (independent work, fused)
//   3) bev_gather: stream 219 MB output, coalesced nontemporal float4 stores;
//      valid slots (~5.6%) read 8 contiguous channels (2x float4) from feats_t.

namespace {
constexpr int kB = 4;
constexpr int kP = 12000;
constexpr int kC = 64;
constexpr int kG = 432 * 496;        // 214272 spatial cells (NZ=1)
constexpr int kGq = kG / 4;          // 53568; divisible by 64 -> wave-uniform b,cc
constexpr int kCSplit = 8;           // channel chunks per (b,g4)
constexpr int kCPer = kC / kCSplit;  // 8 channels per thread
constexpr int kTP = 64;              // p-tile for transpose
constexpr int kBuildBlocks = (kB * kP + 255) / 256;        // 188
constexpr int kTransBlocksPerB = (kP + kTP - 1) / kTP;     // 188
constexpr int kPrepBlocks = kBuildBlocks + kB * kTransBlocksPerB;  // 940
typedef float floatx4 __attribute__((ext_vector_type(4)));
typedef int intx4 __attribute__((ext_vector_type(4)));
}  // namespace

__global__ __launch_bounds__(256) void prep_kernel(const float* __restrict__ pf,
                                                   const int* __restrict__ coords,
                                                   int* __restrict__ inv,
                                                   float* __restrict__ ft) {
    if (blockIdx.x < kBuildBlocks) {
        // ---- build_inv: inv[b*G + s] = global pillar row i ----
        int i = blockIdx.x * blockDim.x + threadIdx.x;
        if (i >= kB * kP) return;
        int b = coords[2 * i];      // dest batch index
        int s = coords[2 * i + 1];  // spatial index; reference mask: s > 0
        if (s > 0 && s < kG && b >= 0 && b < kB) inv[b * kG + s] = i;
        return;
    }
    // ---- transpose: ft[b*P + p][c] = pf[b][c][p] (coalesced both sides via LDS) ----
    __shared__ float tile[kC][kTP + 1];  // [c][p], +1 pad kills bank conflicts
    const int bx = blockIdx.x - kBuildBlocks;
    const int b = bx / kTransBlocksPerB;
    const int p0 = (bx % kTransBlocksPerB) * kTP;
    const int tx = threadIdx.x % kTP;  // p within tile (wave-contiguous)
    const int tg = threadIdx.x / kTP;  // 0..3
    const int p = p0 + tx;

    if (p < kP) {
#pragma unroll
        for (int it = 0; it < 16; ++it) {
            int c = it * 4 + tg;
            tile[c][tx] = pf[((size_t)b * kC + c) * kP + p];
        }
    }
    __syncthreads();

    const int q = threadIdx.x % 16;  // channel quad (float4)
    const int r = threadIdx.x / 16;  // row-in-tile low bits
#pragma unroll
    for (int rr = 0; rr < 4; ++rr) {
        int pp = rr * 16 + r;
        int prow = p0 + pp;
        if (prow < kP) {
            floatx4 v = {tile[4 * q + 0][pp], tile[4 * q + 1][pp],
                         tile[4 * q + 2][pp], tile[4 * q + 3][pp]};
            *reinterpret_cast<floatx4*>(ft + ((size_t)b * kP + prow) * kC + 4 * q) = v;
        }
    }
}

__global__ __launch_bounds__(256) void bev_gather_kernel(const float* __restrict__ ft,
                                                         const int* __restrict__ inv,
                                                         float* __restrict__ out) {
    int t = blockIdx.x * blockDim.x + threadIdx.x;
    int gq = t % kGq;          // fast dim -> coalesced stores/loads
    int bc = t / kGq;          // b * kCSplit + cc   (wave-uniform)
    int cc = bc & (kCSplit - 1);
    int b = bc >> 3;
    if (b >= kB) return;

    // inv is read exactly once -> nontemporal, keep L2 for ft rows.
    const intx4 iv = __builtin_nontemporal_load(
        reinterpret_cast<const intx4*>(inv + b * kG + 4 * gq));
    const int c0 = cc * kCPer;

    float a0[kCPer], a1[kCPer], a2[kCPer], a3[kCPer];
#pragma unroll
    for (int j = 0; j < kCPer; ++j) { a0[j] = 0.f; a1[j] = 0.f; a2[j] = 0.f; a3[j] = 0.f; }

    // Valid slots (~5.6% lane density): 8 contiguous channels = 2x float4 each.
    if (iv.x >= 0) {
        const floatx4* s = reinterpret_cast<const floatx4*>(ft + (size_t)iv.x * kC + c0);
        *reinterpret_cast<floatx4*>(&a0[0]) = s[0];
        *reinterpret_cast<floatx4*>(&a0[4]) = s[1];
    }
    if (iv.y >= 0) {
        const floatx4* s = reinterpret_cast<const floatx4*>(ft + (size_t)iv.y * kC + c0);
        *reinterpret_cast<floatx4*>(&a1[0]) = s[0];
        *reinterpret_cast<floatx4*>(&a1[4]) = s[1];
    }
    if (iv.z >= 0) {
        const floatx4* s = reinterpret_cast<const floatx4*>(ft + (size_t)iv.z * kC + c0);
        *reinterpret_cast<floatx4*>(&a2[0]) = s[0];
        *reinterpret_cast<floatx4*>(&a2[4]) = s[1];
    }
    if (iv.w >= 0) {
        const floatx4* s = reinterpret_cast<const floatx4*>(ft + (size_t)iv.w * kC + c0);
        *reinterpret_cast<floatx4*>(&a3[0]) = s[0];
        *reinterpret_cast<floatx4*>(&a3[4]) = s[1];
    }

    // 8 coalesced nontemporal float4 stores (1KB/wave each); output is write-once.
    float* ob = out + (size_t)b * kC * kG + (size_t)c0 * kG + 4 * gq;
#pragma unroll
    for (int j = 0; j < kCPer; ++j) {
        floatx4 v = {a0[j], a1[j], a2[j], a3[j]};
        __builtin_nontemporal_store(v, reinterpret_cast<floatx4*>(ob + (size_t)j * kG));
    }
}

extern "C" void kernel_launch(void* const* d_in, const int* in_sizes, int n_in,
                              void* d_out, int out_size, void* d_ws, size_t ws_size,
                              hipStream_t stream) {
    const float* pf = (const float*)d_in[0];   // (B, C, P, 1) float32
    const int* coords = (const int*)d_in[1];   // (B*P, 2) int
    float* out = (float*)d_out;                // (B, C, NY, NX) float32
    int* inv = (int*)d_ws;                     // B*G int32 = 3.43 MB
    float* ft = (float*)((char*)d_ws + (size_t)kB * kG * sizeof(int));  // 48000x64 f32 = 12.3 MB

    // inv = -1 (0xFF bytes). Deliberately NOT relying on the 0xAA ws poison:
    // the correctness pass's ws init isn't guaranteed identical to timed passes.
    (void)hipMemsetAsync(inv, 0xFF, (size_t)kB * kG * sizeof(int), stream);

    prep_kernel<<<kPrepBlocks, 256, 0, stream>>>(pf, coords, inv, ft);

    const int total = kB * kCSplit * kGq;      // 1,714,176 threads
    bev_gather_kernel<<<total / 256, 256, 0, stream>>>(ft, inv, out);
}